// Round 7
// baseline (165.501 us; speedup 1.0000x reference)
//
#include <hip/hip_runtime.h>
#include <math.h>

#define N_  32
#define T_  8192
#define D_  64
#define K_  64
#define CHUNKS 32
#define TOK_PER_BLOCK (T_ / CHUNKS)    // 256
#define TB 64                          // tokens per batch
#define NBATCH (TOK_PER_BLOCK / TB)    // 4
#define STATS_PER_N (K_ + 2 * K_ * D_) // 8256
#define XSTR 72                        // f16 stride for Xs/Qs/Pt rows

typedef _Float16 half_t;
typedef __attribute__((ext_vector_type(8)))  _Float16 v8h;
typedef __attribute__((ext_vector_type(4)))  float    v4f;
typedef __attribute__((ext_vector_type(16))) float    v16f;

// ---------------------------------------------------------------------------
// prep (grid 9): blocks 0..7 pack WH (f16 MFMA A-frag order);
// block 8: Ap[k] = 2 log w - 0.5*sum_d(log c + mu^2/c), and zero ssq[32].
// ---------------------------------------------------------------------------
__global__ void prep_kernel(const float* __restrict__ w, const float* __restrict__ mu,
                            const float* __restrict__ cv, float* __restrict__ Ap,
                            half_t* __restrict__ WH, float* __restrict__ ssq) {
    if (blockIdx.x < 8) {
#pragma unroll
        for (int i = 0; i < 4; ++i) {
            const int e = blockIdx.x * 1024 + i * 256 + threadIdx.x;  // 0..8191
            const int j = e & 7, l = (e >> 3) & 63, fs = e >> 9;
            const int tile = fs >> 2, s = fs & 3;
            const int kc = 16 * tile + (l & 15);
            const int f  = 32 * s + 8 * (l >> 4) + j;
            float val;
            if (f < 64) val = mu[kc * 64 + f] / cv[kc * 64 + f];
            else        val = -0.5f / cv[kc * 64 + (f - 64)];
            WH[e] = (half_t)val;
        }
    } else {
        if (threadIdx.x < 32) ssq[threadIdx.x] = 0.f;
        if (threadIdx.x < K_) {
            const int k = threadIdx.x;
            float acc = 0.f;
            for (int d = 0; d < D_; ++d) {
                const int idx = k * D_ + d;
                const float c = cv[idx], m = mu[idx];
                acc += logf(c) + m * m / c;
            }
            Ap[k] = 2.f * logf(w[k]) - 0.5f * acc;
        }
    }
}

// ---------------------------------------------------------------------------
// main: grid (32, 32) = 1024 blocks, block 256 (4 waves).
// R6-validated compute. New: double-buffered Xs/Qs; staging of batch b+1 runs
// under Phase A of batch b -> 2 barriers/batch instead of 3, global-load
// latency hidden under Phase A compute.
// ---------------------------------------------------------------------------
__launch_bounds__(256, 3)
__global__ void main_kernel(const float* __restrict__ x, const float* __restrict__ Ap,
                            const half_t* __restrict__ WH, float* __restrict__ outbuf,
                            int mode) {
    __shared__ half_t Xs[2][TB][XSTR];   // 18 KB
    __shared__ half_t Qs[2][TB][XSTR];   // 18 KB
    __shared__ half_t Pt[K_][XSTR];      //  9 KB (transposed p: row=kc, col=token)
    __shared__ float  s0sh[4][64];       //  1 KB

    const int tid  = threadIdx.x;
    const int lane = tid & 63;
    const int wv   = tid >> 6;
    const int chunk = blockIdx.x;
    const int n     = blockIdx.y;
    const int q     = lane >> 4;
    const int c0    = lane & 15;

    // resident weight A-frags
    v8h Wf[16];
#pragma unroll
    for (int t = 0; t < 4; ++t)
#pragma unroll
        for (int s = 0; s < 4; ++s)
            Wf[t * 4 + s] = *(const v8h*)(WH + (size_t)((t * 4 + s) * 64 + lane) * 8);

    float apv[16];
#pragma unroll
    for (int t = 0; t < 4; ++t)
#pragma unroll
        for (int r = 0; r < 4; ++r) apv[t * 4 + r] = Ap[16 * t + 4 * q + r];

    float S0loc[16];
#pragma unroll
    for (int j = 0; j < 16; ++j) S0loc[j] = 0.f;

    const int sig = wv >> 1;
    const int dh  = wv & 1;
    v16f accB[2];
#pragma unroll
    for (int m = 0; m < 2; ++m)
#pragma unroll
        for (int r = 0; r < 16; ++r) accB[m][r] = 0.f;

    const size_t xbase = ((size_t)n * T_ + (size_t)chunk * TOK_PER_BLOCK) * (size_t)D_;
    const int tg0 = tid >> 3, uu = tid & 7;
    const int tg1 = (256 + tid) >> 3;

    auto load4 = [&](int batch, float4* Rv) {
        const float* xb = x + xbase + (size_t)batch * TB * D_;
        Rv[0] = *(const float4*)(xb + tg0 * 64 + uu * 8);
        Rv[1] = *(const float4*)(xb + tg0 * 64 + uu * 8 + 4);
        Rv[2] = *(const float4*)(xb + tg1 * 64 + uu * 8);
        Rv[3] = *(const float4*)(xb + tg1 * 64 + uu * 8 + 4);
    };
    auto stage = [&](int buf, const float4* Rv) {
#pragma unroll
        for (int i = 0; i < 2; ++i) {
            const int t = (i == 0) ? tg0 : tg1;
            const float4 v0 = Rv[2 * i], v1 = Rv[2 * i + 1];
            v8h xh, qh;
            xh[0] = (half_t)v0.x; xh[1] = (half_t)v0.y; xh[2] = (half_t)v0.z; xh[3] = (half_t)v0.w;
            xh[4] = (half_t)v1.x; xh[5] = (half_t)v1.y; xh[6] = (half_t)v1.z; xh[7] = (half_t)v1.w;
            qh[0] = (half_t)(v0.x * v0.x); qh[1] = (half_t)(v0.y * v0.y);
            qh[2] = (half_t)(v0.z * v0.z); qh[3] = (half_t)(v0.w * v0.w);
            qh[4] = (half_t)(v1.x * v1.x); qh[5] = (half_t)(v1.y * v1.y);
            qh[6] = (half_t)(v1.z * v1.z); qh[7] = (half_t)(v1.w * v1.w);
            *(v8h*)&Xs[buf][t][uu * 8] = xh;
            *(v8h*)&Qs[buf][t][uu * 8] = qh;
        }
    };

    {
        float4 R[4];
        load4(0, R);
        stage(0, R);
    }
    __syncthreads();

#pragma unroll 1
    for (int batch = 0; batch < NBATCH; ++batch) {
        const int buf = batch & 1;
        const bool more = (batch + 1 < NBATCH);
        float4 Rn[4];
        if (more) load4(batch + 1, Rn);   // in flight under Phase A

        // ---------------- Phase A (reads buf) ----------------
        {
            const int tok = 16 * wv + c0;
            v4f acc[4];
#pragma unroll
            for (int t = 0; t < 4; ++t) acc[t] = (v4f)(0.f);
#pragma unroll
            for (int s = 0; s < 4; ++s) {
                const half_t* src = (s < 2) ? &Xs[buf][0][0] : &Qs[buf][0][0];
                const int d0 = (s & 1) * 32 + q * 8;
                const v8h bf = *(const v8h*)(src + tok * XSTR + d0);
#pragma unroll
                for (int t = 0; t < 4; ++t)
                    acc[t] = __builtin_amdgcn_mfma_f32_16x16x32_f16(Wf[t * 4 + s], bf, acc[t], 0, 0, 0);
            }
            float pv[16];
            float m = -1e30f;
#pragma unroll
            for (int t = 0; t < 4; ++t)
#pragma unroll
                for (int r = 0; r < 4; ++r) {
                    const float lg = acc[t][r] + apv[t * 4 + r];
                    pv[t * 4 + r] = lg;
                    m = fmaxf(m, lg);
                }
            m = fmaxf(m, __shfl_xor(m, 16, 64));
            m = fmaxf(m, __shfl_xor(m, 32, 64));
            float ssum = 0.f;
#pragma unroll
            for (int j = 0; j < 16; ++j) { pv[j] = __expf(pv[j] - m); ssum += pv[j]; }
            ssum += __shfl_xor(ssum, 16, 64);
            ssum += __shfl_xor(ssum, 32, 64);
            const float rs = 1.f / ssum;
#pragma unroll
            for (int j = 0; j < 16; ++j) { pv[j] *= rs; S0loc[j] += pv[j]; }
#pragma unroll
            for (int t = 0; t < 4; ++t)
#pragma unroll
                for (int r = 0; r < 4; ++r)
                    Pt[16 * t + 4 * q + r][tok] = (half_t)pv[t * 4 + r];
        }
        if (more) stage(buf ^ 1, Rn);     // other buffer; its last reader done
        __syncthreads();                   // Pt ready + next batch staged

        // ---------------- Phase B (reads buf + Pt) ----------------
        {
            const half_t* Bsrc = (sig == 0) ? &Xs[buf][0][0] : &Qs[buf][0][0];
            const int m   = lane & 31;
            const int h   = lane >> 5;
            const int d   = 32 * dh + m;
            const half_t* Arow0 = &Pt[m][0];
            const half_t* Arow1 = &Pt[32 + m][0];
#pragma unroll
            for (int st = 0; st < 4; ++st) {
                const int tB = 16 * st + 8 * h;
                const v8h a0 = *(const v8h*)(Arow0 + tB);
                const v8h a1 = *(const v8h*)(Arow1 + tB);
                v8h bf;
#pragma unroll
                for (int j = 0; j < 8; ++j)
                    bf[j] = Bsrc[(tB + j) * XSTR + d];
                accB[0] = __builtin_amdgcn_mfma_f32_32x32x16_f16(a0, bf, accB[0], 0, 0, 0);
                accB[1] = __builtin_amdgcn_mfma_f32_32x32x16_f16(a1, bf, accB[1], 0, 0, 0);
            }
        }
        __syncthreads();                   // Phase B done -> Pt/buf reusable
    }

    // -------- flush --------
#pragma unroll
    for (int j = 0; j < 16; ++j) {
        float v = S0loc[j];
        v += __shfl_xor(v, 1, 64);
        v += __shfl_xor(v, 2, 64);
        v += __shfl_xor(v, 4, 64);
        v += __shfl_xor(v, 8, 64);
        S0loc[j] = v;
    }
    if (c0 == 0) {
#pragma unroll
        for (int t = 0; t < 4; ++t)
#pragma unroll
            for (int r = 0; r < 4; ++r)
                s0sh[wv][16 * t + 4 * q + r] = S0loc[t * 4 + r];
    }
    __syncthreads();

    if (mode == 1) {
        float* dstb = outbuf + (size_t)(n * CHUNKS + chunk) * STATS_PER_N;
        if (tid < 64)
            dstb[tid] = s0sh[0][tid] + s0sh[1][tid] + s0sh[2][tid] + s0sh[3][tid];
        const int d = 32 * dh + (lane & 31);
        float* dst = dstb + 64 + sig * 4096;
#pragma unroll
        for (int mt = 0; mt < 2; ++mt)
#pragma unroll
            for (int r = 0; r < 16; ++r) {
                const int kc = 32 * mt + (r & 3) + 8 * (r >> 2) + 4 * (lane >> 5);
                dst[kc * 64 + d] = accB[mt][r];
            }
    } else {
        float* sb = outbuf + (size_t)n * STATS_PER_N;
        if (tid < 64)
            atomicAdd(&sb[tid], s0sh[0][tid] + s0sh[1][tid] + s0sh[2][tid] + s0sh[3][tid]);
        const int d = 32 * dh + (lane & 31);
        float* dst = sb + 64 + sig * 4096;
#pragma unroll
        for (int mt = 0; mt < 2; ++mt)
#pragma unroll
            for (int r = 0; r < 16; ++r) {
                const int kc = 32 * mt + (r & 3) + 8 * (r >> 2) + 4 * (lane >> 5);
                atomicAdd(&dst[kc * 64 + d], accB[mt][r]);
            }
    }
}

// ---------------------------------------------------------------------------
// reduce_pow (grid (33, N)): sum partials over chunks, apply v0/v1/v2 transform
// + signed sqrt, write us in OUTPUT order; one ssq atomic per block.
// ---------------------------------------------------------------------------
__global__ void reduce_pow_kernel(const float* __restrict__ partials,
                                  const float* __restrict__ w, const float* __restrict__ mu,
                                  const float* __restrict__ cv,
                                  float* __restrict__ us, float* __restrict__ ssq) {
    __shared__ float red[4];
    const int e = blockIdx.x * 256 + threadIdx.x;
    const int n = blockIdx.y;
    float u = 0.f;
    if (e < STATS_PER_N) {
        const float* base = partials + (size_t)n * CHUNKS * STATS_PER_N;
        float sv = 0.f;
#pragma unroll 8
        for (int c = 0; c < CHUNKS; ++c) sv += base[(size_t)c * STATS_PER_N + e];
        float v; int oidx;
        if (e < 64) {
            const float wv = w[e];
            v = (sv - (float)T_ * wv) * rsqrtf(wv);
            oidx = e * 129;
        } else if (e < 64 + 4096) {
            const int idx = e - 64, k = idx >> 6, d = idx & 63;
            float s0v = 0.f;
#pragma unroll 8
            for (int c = 0; c < CHUNKS; ++c) s0v += base[(size_t)c * STATS_PER_N + k];
            v = (sv - mu[idx] * s0v) * rsqrtf(w[k] * cv[idx]);
            oidx = k * 129 + 1 + d;
        } else {
            const int idx = e - 4160, k = idx >> 6, d = idx & 63;
            float s0v = 0.f, s1v = 0.f;
#pragma unroll 4
            for (int c = 0; c < CHUNKS; ++c) {
                s0v += base[(size_t)c * STATS_PER_N + k];
                s1v += base[(size_t)c * STATS_PER_N + 64 + idx];
            }
            const float m_ = mu[idx], c_ = cv[idx];
            v = (sv - 2.f * m_ * s1v + (m_ * m_ - c_) * s0v) * (rsqrtf(2.f * w[k]) / c_);
            oidx = k * 129 + 65 + d;
        }
        u = (v >= 0.f) ? sqrtf(v) : -sqrtf(-v);
        us[(size_t)n * STATS_PER_N + oidx] = u;
    }
    float ss = u * u;
#pragma unroll
    for (int off = 32; off > 0; off >>= 1) ss += __shfl_xor(ss, off, 64);
    if ((threadIdx.x & 63) == 0) red[threadIdx.x >> 6] = ss;
    __syncthreads();
    if (threadIdx.x == 0)
        atomicAdd(&ssq[n], red[0] + red[1] + red[2] + red[3]);
}

// ---------------------------------------------------------------------------
// scale (grid (33, N)): out = us * rsqrt(ssq[n])
// ---------------------------------------------------------------------------
__global__ void scale_kernel(const float* __restrict__ us, const float* __restrict__ ssq,
                             float* __restrict__ out) {
    const int e = blockIdx.x * 256 + threadIdx.x;
    const int n = blockIdx.y;
    if (e < STATS_PER_N)
        out[(size_t)n * STATS_PER_N + e] = us[(size_t)n * STATS_PER_N + e] * rsqrtf(ssq[n]);
}

// ---------------------------------------------------------------------------
// fallback finalize (small-ws atomic path), same as R6.
// ---------------------------------------------------------------------------
__global__ void fin_kernel(const float* __restrict__ w, const float* __restrict__ mu,
                           const float* __restrict__ cv, const float* __restrict__ stats,
                           float* __restrict__ out) {
    __shared__ float us[STATS_PER_N];
    __shared__ float red[4];
    const int n   = blockIdx.x;
    const int tid = threadIdx.x;
    const float* sb = stats + (size_t)n * STATS_PER_N;

    float ss = 0.f;
    if (tid < 64) {
        const float wv = w[tid];
        const float v = (sb[tid] - (float)T_ * wv) * rsqrtf(wv);
        const float u = (v >= 0.f) ? sqrtf(v) : -sqrtf(-v);
        us[tid * 129] = u;
        ss = fmaf(u, u, ss);
    }
#pragma unroll 1
    for (int i = 0; i < 16; ++i) {
        const int idx = i * 256 + tid;
        const int k = idx >> 6, d = idx & 63;
        const float v = (sb[64 + idx] - mu[idx] * sb[k]) * rsqrtf(w[k] * cv[idx]);
        const float u = (v >= 0.f) ? sqrtf(v) : -sqrtf(-v);
        us[k * 129 + 1 + d] = u;
        ss = fmaf(u, u, ss);
    }
#pragma unroll 1
    for (int i = 0; i < 16; ++i) {
        const int idx = i * 256 + tid;
        const int k = idx >> 6, d = idx & 63;
        const float m_ = mu[idx], c_ = cv[idx];
        const float s1v = sb[64 + idx], s2v = sb[64 + 4096 + idx];
        const float v = (s2v - 2.f * m_ * s1v + (m_ * m_ - c_) * sb[k]) *
                        (rsqrtf(2.f * w[k]) / c_);
        const float u = (v >= 0.f) ? sqrtf(v) : -sqrtf(-v);
        us[k * 129 + 65 + d] = u;
        ss = fmaf(u, u, ss);
    }
#pragma unroll
    for (int off = 32; off > 0; off >>= 1) ss += __shfl_xor(ss, off, 64);
    if ((tid & 63) == 0) red[tid >> 6] = ss;
    __syncthreads();
    const float tot = red[0] + red[1] + red[2] + red[3];
    const float rn = rsqrtf(tot);
    for (int e = tid; e < STATS_PER_N; e += 256)
        out[(size_t)n * STATS_PER_N + e] = us[e] * rn;
}

// ---------------------------------------------------------------------------
extern "C" void kernel_launch(void* const* d_in, const int* in_sizes, int n_in,
                              void* d_out, int out_size, void* d_ws, size_t ws_size,
                              hipStream_t stream) {
    const float* x  = (const float*)d_in[0];
    const float* w  = (const float*)d_in[1];
    const float* mu = (const float*)d_in[2];
    const float* cv = (const float*)d_in[3];
    float* out = (float*)d_out;

    const size_t part_elems = (size_t)CHUNKS * N_ * STATS_PER_N;   // 8.45M floats
    const size_t us_elems   = (size_t)N_ * STATS_PER_N;
    const size_t need_big = (part_elems + us_elems + 32 + K_ + (size_t)K_ * 64) * sizeof(float);

    if (ws_size >= need_big) {
        float* partials = (float*)d_ws;
        float* us  = partials + part_elems;
        float* ssq = us + us_elems;
        float* Ap  = ssq + 32;
        half_t* WH = (half_t*)(Ap + K_);

        prep_kernel<<<9, 256, 0, stream>>>(w, mu, cv, Ap, WH, ssq);
        main_kernel<<<dim3(CHUNKS, N_), 256, 0, stream>>>(x, Ap, WH, partials, 1);
        reduce_pow_kernel<<<dim3(33, N_), 256, 0, stream>>>(partials, w, mu, cv, us, ssq);
        scale_kernel<<<dim3(33, N_), 256, 0, stream>>>(us, ssq, out);
    } else {
        float* stats = (float*)d_ws;
        float* ssq = stats + us_elems;          // reused as dummy zero area
        float* Ap  = ssq + 32;
        half_t* WH = (half_t*)(Ap + K_);

        hipMemsetAsync(stats, 0, us_elems * sizeof(float), stream);
        prep_kernel<<<9, 256, 0, stream>>>(w, mu, cv, Ap, WH, ssq);
        main_kernel<<<dim3(CHUNKS, N_), 256, 0, stream>>>(x, Ap, WH, stats, 0);
        fin_kernel<<<N_, 256, 0, stream>>>(w, mu, cv, stats, out);
    }
}

// Round 8
// 154.168 us; speedup vs baseline: 1.0735x; 1.0735x over previous
//
#include <hip/hip_runtime.h>
#include <math.h>

#define N_  32
#define T_  8192
#define D_  64
#define K_  64
#define CHUNKS 32
#define TOK_PER_BLOCK (T_ / CHUNKS)    // 256
#define TB 64                          // tokens per batch
#define NBATCH (TOK_PER_BLOCK / TB)    // 4
#define STATS_PER_N (K_ + 2 * K_ * D_) // 8256
#define XSTR 72                        // f16 stride for Xs/Qs/Pt rows

typedef _Float16 half_t;
typedef __attribute__((ext_vector_type(8)))  _Float16 v8h;
typedef __attribute__((ext_vector_type(4)))  float    v4f;
typedef __attribute__((ext_vector_type(16))) float    v16f;

// ---------------------------------------------------------------------------
// prep (grid 9): blocks 0..7 pack WH (f16 MFMA A-frag order);
// block 8: Ap[k] = 2 log w - 0.5*sum_d(log c + mu^2/c), and zero ssq[32].
// ---------------------------------------------------------------------------
__global__ void prep_kernel(const float* __restrict__ w, const float* __restrict__ mu,
                            const float* __restrict__ cv, float* __restrict__ Ap,
                            half_t* __restrict__ WH, float* __restrict__ ssq) {
    if (blockIdx.x < 8) {
#pragma unroll
        for (int i = 0; i < 4; ++i) {
            const int e = blockIdx.x * 1024 + i * 256 + threadIdx.x;  // 0..8191
            const int j = e & 7, l = (e >> 3) & 63, fs = e >> 9;
            const int tile = fs >> 2, s = fs & 3;
            const int kc = 16 * tile + (l & 15);
            const int f  = 32 * s + 8 * (l >> 4) + j;
            float val;
            if (f < 64) val = mu[kc * 64 + f] / cv[kc * 64 + f];
            else        val = -0.5f / cv[kc * 64 + (f - 64)];
            WH[e] = (half_t)val;
        }
    } else {
        if (threadIdx.x < 32) ssq[threadIdx.x] = 0.f;
        if (threadIdx.x < K_) {
            const int k = threadIdx.x;
            float acc = 0.f;
            for (int d = 0; d < D_; ++d) {
                const int idx = k * D_ + d;
                const float c = cv[idx], m = mu[idx];
                acc += logf(c) + m * m / c;
            }
            Ap[k] = 2.f * logf(w[k]) - 0.5f * acc;
        }
    }
}

// ---------------------------------------------------------------------------
// main: grid (32, 32) = 1024 blocks, block 256 (4 waves).
// Per batch: Phase A builds its MFMA B-frags DIRECTLY from registers loaded
// from global (no LDS reads in A); the same registers are staged to Xs/Qs
// for Phase B. Single-buffered LDS (28.6 KB -> 5 blocks/CU residency; R7's
// 47 KB double-buffer cut residency to 3 and regressed). 2 barriers/batch.
// ---------------------------------------------------------------------------
__launch_bounds__(256, 3)
__global__ void main_kernel(const float* __restrict__ x, const float* __restrict__ Ap,
                            const half_t* __restrict__ WH, float* __restrict__ outbuf,
                            int mode) {
    __shared__ half_t Xs[TB][XSTR];   // 9.0 KB
    __shared__ half_t Qs[TB][XSTR];   // 9.0 KB
    __shared__ half_t Pt[K_][XSTR];   // 9.0 KB (transposed p: row=kc, col=token)
    __shared__ float  s0sh[4][64];    // 1.0 KB

    const int tid  = threadIdx.x;
    const int lane = tid & 63;
    const int wv   = tid >> 6;
    const int chunk = blockIdx.x;
    const int n     = blockIdx.y;
    const int q     = lane >> 4;
    const int c0    = lane & 15;
    const int tok   = 16 * wv + c0;   // this lane's token within the batch

    // resident weight A-frags
    v8h Wf[16];
#pragma unroll
    for (int t = 0; t < 4; ++t)
#pragma unroll
        for (int s = 0; s < 4; ++s)
            Wf[t * 4 + s] = *(const v8h*)(WH + (size_t)((t * 4 + s) * 64 + lane) * 8);

    float apv[16];
#pragma unroll
    for (int t = 0; t < 4; ++t)
#pragma unroll
        for (int r = 0; r < 4; ++r) apv[t * 4 + r] = Ap[16 * t + 4 * q + r];

    float S0loc[16];
#pragma unroll
    for (int j = 0; j < 16; ++j) S0loc[j] = 0.f;

    const int sig = wv >> 1;
    const int dh  = wv & 1;
    v16f accB[2];
#pragma unroll
    for (int m = 0; m < 2; ++m)
#pragma unroll
        for (int r = 0; r < 16; ++r) accB[m][r] = 0.f;

    const size_t xbase = ((size_t)n * T_ + (size_t)chunk * TOK_PER_BLOCK) * (size_t)D_;
    // Phase-A load geometry: lane reads token `tok`, d in [8q,8q+8) and [32+8q,+8)
    const float* xrow0 = x + xbase + tok * 64 + 8 * q;

    // preload batch 0
    float4 R[4];
    R[0] = *(const float4*)(xrow0);
    R[1] = *(const float4*)(xrow0 + 4);
    R[2] = *(const float4*)(xrow0 + 32);
    R[3] = *(const float4*)(xrow0 + 36);

#pragma unroll 1
    for (int batch = 0; batch < NBATCH; ++batch) {
        // ---- convert current R -> frags (registers), stage to LDS for Phase B ----
        v8h xh0, xh1, qh0, qh1;
        {
            const float4 a = R[0], b = R[1], c = R[2], d = R[3];
            xh0[0] = (half_t)a.x; xh0[1] = (half_t)a.y; xh0[2] = (half_t)a.z; xh0[3] = (half_t)a.w;
            xh0[4] = (half_t)b.x; xh0[5] = (half_t)b.y; xh0[6] = (half_t)b.z; xh0[7] = (half_t)b.w;
            xh1[0] = (half_t)c.x; xh1[1] = (half_t)c.y; xh1[2] = (half_t)c.z; xh1[3] = (half_t)c.w;
            xh1[4] = (half_t)d.x; xh1[5] = (half_t)d.y; xh1[6] = (half_t)d.z; xh1[7] = (half_t)d.w;
            qh0[0] = (half_t)(a.x * a.x); qh0[1] = (half_t)(a.y * a.y);
            qh0[2] = (half_t)(a.z * a.z); qh0[3] = (half_t)(a.w * a.w);
            qh0[4] = (half_t)(b.x * b.x); qh0[5] = (half_t)(b.y * b.y);
            qh0[6] = (half_t)(b.z * b.z); qh0[7] = (half_t)(b.w * b.w);
            qh1[0] = (half_t)(c.x * c.x); qh1[1] = (half_t)(c.y * c.y);
            qh1[2] = (half_t)(c.z * c.z); qh1[3] = (half_t)(c.w * c.w);
            qh1[4] = (half_t)(d.x * d.x); qh1[5] = (half_t)(d.y * d.y);
            qh1[6] = (half_t)(d.z * d.z); qh1[7] = (half_t)(d.w * d.w);
            *(v8h*)&Xs[tok][8 * q]      = xh0;
            *(v8h*)&Xs[tok][32 + 8 * q] = xh1;
            *(v8h*)&Qs[tok][8 * q]      = qh0;
            *(v8h*)&Qs[tok][32 + 8 * q] = qh1;
        }

        // ---- prefetch next batch (latency hidden under A-MFMA + softmax + B) ----
        if (batch + 1 < NBATCH) {
            const float* xr = xrow0 + (size_t)(batch + 1) * TB * D_;
            R[0] = *(const float4*)(xr);
            R[1] = *(const float4*)(xr + 4);
            R[2] = *(const float4*)(xr + 32);
            R[3] = *(const float4*)(xr + 36);
        }

        // ---------------- Phase A (register frags only) ----------------
        {
            v4f acc[4];
#pragma unroll
            for (int t = 0; t < 4; ++t) acc[t] = (v4f)(0.f);
#pragma unroll
            for (int t = 0; t < 4; ++t) {
                acc[t] = __builtin_amdgcn_mfma_f32_16x16x32_f16(Wf[t * 4 + 0], xh0, acc[t], 0, 0, 0);
                acc[t] = __builtin_amdgcn_mfma_f32_16x16x32_f16(Wf[t * 4 + 1], xh1, acc[t], 0, 0, 0);
                acc[t] = __builtin_amdgcn_mfma_f32_16x16x32_f16(Wf[t * 4 + 2], qh0, acc[t], 0, 0, 0);
                acc[t] = __builtin_amdgcn_mfma_f32_16x16x32_f16(Wf[t * 4 + 3], qh1, acc[t], 0, 0, 0);
            }
            float pv[16];
            float m = -1e30f;
#pragma unroll
            for (int t = 0; t < 4; ++t)
#pragma unroll
                for (int r = 0; r < 4; ++r) {
                    const float lg = acc[t][r] + apv[t * 4 + r];
                    pv[t * 4 + r] = lg;
                    m = fmaxf(m, lg);
                }
            m = fmaxf(m, __shfl_xor(m, 16, 64));
            m = fmaxf(m, __shfl_xor(m, 32, 64));
            float ssum = 0.f;
#pragma unroll
            for (int j = 0; j < 16; ++j) { pv[j] = __expf(pv[j] - m); ssum += pv[j]; }
            ssum += __shfl_xor(ssum, 16, 64);
            ssum += __shfl_xor(ssum, 32, 64);
            const float rs = 1.f / ssum;
#pragma unroll
            for (int j = 0; j < 16; ++j) { pv[j] *= rs; S0loc[j] += pv[j]; }
#pragma unroll
            for (int t = 0; t < 4; ++t)
#pragma unroll
                for (int r = 0; r < 4; ++r)
                    Pt[16 * t + 4 * q + r][tok] = (half_t)pv[t * 4 + r];
        }
        __syncthreads();   // Xs/Qs/Pt all visible

        // ---------------- Phase B ----------------
        {
            const half_t* Bsrc = (sig == 0) ? &Xs[0][0] : &Qs[0][0];
            const int m   = lane & 31;
            const int h   = lane >> 5;
            const int d   = 32 * dh + m;
            const half_t* Arow0 = &Pt[m][0];
            const half_t* Arow1 = &Pt[32 + m][0];
#pragma unroll
            for (int st = 0; st < 4; ++st) {
                const int tB = 16 * st + 8 * h;
                const v8h a0 = *(const v8h*)(Arow0 + tB);
                const v8h a1 = *(const v8h*)(Arow1 + tB);
                v8h bf;
#pragma unroll
                for (int j = 0; j < 8; ++j)
                    bf[j] = Bsrc[(tB + j) * XSTR + d];
                accB[0] = __builtin_amdgcn_mfma_f32_32x32x16_f16(a0, bf, accB[0], 0, 0, 0);
                accB[1] = __builtin_amdgcn_mfma_f32_32x32x16_f16(a1, bf, accB[1], 0, 0, 0);
            }
        }
        __syncthreads();   // Phase B done -> LDS reusable next batch
    }

    // -------- flush --------
#pragma unroll
    for (int j = 0; j < 16; ++j) {
        float v = S0loc[j];
        v += __shfl_xor(v, 1, 64);
        v += __shfl_xor(v, 2, 64);
        v += __shfl_xor(v, 4, 64);
        v += __shfl_xor(v, 8, 64);
        S0loc[j] = v;
    }
    if (c0 == 0) {
#pragma unroll
        for (int t = 0; t < 4; ++t)
#pragma unroll
            for (int r = 0; r < 4; ++r)
                s0sh[wv][16 * t + 4 * q + r] = S0loc[t * 4 + r];
    }
    __syncthreads();

    if (mode == 1) {
        float* dstb = outbuf + (size_t)(n * CHUNKS + chunk) * STATS_PER_N;
        if (tid < 64)
            dstb[tid] = s0sh[0][tid] + s0sh[1][tid] + s0sh[2][tid] + s0sh[3][tid];
        const int d = 32 * dh + (lane & 31);
        float* dst = dstb + 64 + sig * 4096;
#pragma unroll
        for (int mt = 0; mt < 2; ++mt)
#pragma unroll
            for (int r = 0; r < 16; ++r) {
                const int kc = 32 * mt + (r & 3) + 8 * (r >> 2) + 4 * (lane >> 5);
                dst[kc * 64 + d] = accB[mt][r];
            }
    } else {
        float* sb = outbuf + (size_t)n * STATS_PER_N;
        if (tid < 64)
            atomicAdd(&sb[tid], s0sh[0][tid] + s0sh[1][tid] + s0sh[2][tid] + s0sh[3][tid]);
        const int d = 32 * dh + (lane & 31);
        float* dst = sb + 64 + sig * 4096;
#pragma unroll
        for (int mt = 0; mt < 2; ++mt)
#pragma unroll
            for (int r = 0; r < 16; ++r) {
                const int kc = 32 * mt + (r & 3) + 8 * (r >> 2) + 4 * (lane >> 5);
                atomicAdd(&dst[kc * 64 + d], accB[mt][r]);
            }
    }
}

// ---------------------------------------------------------------------------
// reduce_pow (grid (33, N)): sum partials over chunks, apply v0/v1/v2 transform
// + signed sqrt, write us in OUTPUT order; one ssq atomic per block.
// ---------------------------------------------------------------------------
__global__ void reduce_pow_kernel(const float* __restrict__ partials,
                                  const float* __restrict__ w, const float* __restrict__ mu,
                                  const float* __restrict__ cv,
                                  float* __restrict__ us, float* __restrict__ ssq) {
    __shared__ float red[4];
    const int e = blockIdx.x * 256 + threadIdx.x;
    const int n = blockIdx.y;
    float u = 0.f;
    if (e < STATS_PER_N) {
        const float* base = partials + (size_t)n * CHUNKS * STATS_PER_N;
        float sv = 0.f;
#pragma unroll 8
        for (int c = 0; c < CHUNKS; ++c) sv += base[(size_t)c * STATS_PER_N + e];
        float v; int oidx;
        if (e < 64) {
            const float wv = w[e];
            v = (sv - (float)T_ * wv) * rsqrtf(wv);
            oidx = e * 129;
        } else if (e < 64 + 4096) {
            const int idx = e - 64, k = idx >> 6, d = idx & 63;
            float s0v = 0.f;
#pragma unroll 8
            for (int c = 0; c < CHUNKS; ++c) s0v += base[(size_t)c * STATS_PER_N + k];
            v = (sv - mu[idx] * s0v) * rsqrtf(w[k] * cv[idx]);
            oidx = k * 129 + 1 + d;
        } else {
            const int idx = e - 4160, k = idx >> 6, d = idx & 63;
            float s0v = 0.f, s1v = 0.f;
#pragma unroll 4
            for (int c = 0; c < CHUNKS; ++c) {
                s0v += base[(size_t)c * STATS_PER_N + k];
                s1v += base[(size_t)c * STATS_PER_N + 64 + idx];
            }
            const float m_ = mu[idx], c_ = cv[idx];
            v = (sv - 2.f * m_ * s1v + (m_ * m_ - c_) * s0v) * (rsqrtf(2.f * w[k]) / c_);
            oidx = k * 129 + 65 + d;
        }
        u = (v >= 0.f) ? sqrtf(v) : -sqrtf(-v);
        us[(size_t)n * STATS_PER_N + oidx] = u;
    }
    float ss = u * u;
#pragma unroll
    for (int off = 32; off > 0; off >>= 1) ss += __shfl_xor(ss, off, 64);
    if ((threadIdx.x & 63) == 0) red[threadIdx.x >> 6] = ss;
    __syncthreads();
    if (threadIdx.x == 0)
        atomicAdd(&ssq[n], red[0] + red[1] + red[2] + red[3]);
}

// ---------------------------------------------------------------------------
// scale (grid (33, N)): out = us * rsqrt(ssq[n])
// ---------------------------------------------------------------------------
__global__ void scale_kernel(const float* __restrict__ us, const float* __restrict__ ssq,
                             float* __restrict__ out) {
    const int e = blockIdx.x * 256 + threadIdx.x;
    const int n = blockIdx.y;
    if (e < STATS_PER_N)
        out[(size_t)n * STATS_PER_N + e] = us[(size_t)n * STATS_PER_N + e] * rsqrtf(ssq[n]);
}

// ---------------------------------------------------------------------------
// fallback finalize (small-ws atomic path).
// ---------------------------------------------------------------------------
__global__ void fin_kernel(const float* __restrict__ w, const float* __restrict__ mu,
                           const float* __restrict__ cv, const float* __restrict__ stats,
                           float* __restrict__ out) {
    __shared__ float us[STATS_PER_N];
    __shared__ float red[4];
    const int n   = blockIdx.x;
    const int tid = threadIdx.x;
    const float* sb = stats + (size_t)n * STATS_PER_N;

    float ss = 0.f;
    if (tid < 64) {
        const float wv = w[tid];
        const float v = (sb[tid] - (float)T_ * wv) * rsqrtf(wv);
        const float u = (v >= 0.f) ? sqrtf(v) : -sqrtf(-v);
        us[tid * 129] = u;
        ss = fmaf(u, u, ss);
    }
#pragma unroll 1
    for (int i = 0; i < 16; ++i) {
        const int idx = i * 256 + tid;
        const int k = idx >> 6, d = idx & 63;
        const float v = (sb[64 + idx] - mu[idx] * sb[k]) * rsqrtf(w[k] * cv[idx]);
        const float u = (v >= 0.f) ? sqrtf(v) : -sqrtf(-v);
        us[k * 129 + 1 + d] = u;
        ss = fmaf(u, u, ss);
    }
#pragma unroll 1
    for (int i = 0; i < 16; ++i) {
        const int idx = i * 256 + tid;
        const int k = idx >> 6, d = idx & 63;
        const float m_ = mu[idx], c_ = cv[idx];
        const float s1v = sb[64 + idx], s2v = sb[64 + 4096 + idx];
        const float v = (s2v - 2.f * m_ * s1v + (m_ * m_ - c_) * sb[k]) *
                        (rsqrtf(2.f * w[k]) / c_);
        const float u = (v >= 0.f) ? sqrtf(v) : -sqrtf(-v);
        us[k * 129 + 65 + d] = u;
        ss = fmaf(u, u, ss);
    }
#pragma unroll
    for (int off = 32; off > 0; off >>= 1) ss += __shfl_xor(ss, off, 64);
    if ((tid & 63) == 0) red[tid >> 6] = ss;
    __syncthreads();
    const float tot = red[0] + red[1] + red[2] + red[3];
    const float rn = rsqrtf(tot);
    for (int e = tid; e < STATS_PER_N; e += 256)
        out[(size_t)n * STATS_PER_N + e] = us[e] * rn;
}

// ---------------------------------------------------------------------------
extern "C" void kernel_launch(void* const* d_in, const int* in_sizes, int n_in,
                              void* d_out, int out_size, void* d_ws, size_t ws_size,
                              hipStream_t stream) {
    const float* x  = (const float*)d_in[0];
    const float* w  = (const float*)d_in[1];
    const float* mu = (const float*)d_in[2];
    const float* cv = (const float*)d_in[3];
    float* out = (float*)d_out;

    const size_t part_elems = (size_t)CHUNKS * N_ * STATS_PER_N;   // 8.45M floats
    const size_t us_elems   = (size_t)N_ * STATS_PER_N;
    const size_t need_big = (part_elems + us_elems + 32 + K_ + (size_t)K_ * 64) * sizeof(float);

    if (ws_size >= need_big) {
        float* partials = (float*)d_ws;
        float* us  = partials + part_elems;
        float* ssq = us + us_elems;
        float* Ap  = ssq + 32;
        half_t* WH = (half_t*)(Ap + K_);

        prep_kernel<<<9, 256, 0, stream>>>(w, mu, cv, Ap, WH, ssq);
        main_kernel<<<dim3(CHUNKS, N_), 256, 0, stream>>>(x, Ap, WH, partials, 1);
        reduce_pow_kernel<<<dim3(33, N_), 256, 0, stream>>>(partials, w, mu, cv, us, ssq);
        scale_kernel<<<dim3(33, N_), 256, 0, stream>>>(us, ssq, out);
    } else {
        float* stats = (float*)d_ws;
        float* ssq = stats + us_elems;
        float* Ap  = ssq + 32;
        half_t* WH = (half_t*)(Ap + K_);

        hipMemsetAsync(stats, 0, us_elems * sizeof(float), stream);
        prep_kernel<<<9, 256, 0, stream>>>(w, mu, cv, Ap, WH, ssq);
        main_kernel<<<dim3(CHUNKS, N_), 256, 0, stream>>>(x, Ap, WH, stats, 0);
        fin_kernel<<<N_, 256, 0, stream>>>(w, mu, cv, stats, out);
    }
}